// Round 7
// baseline (1792.697 us; speedup 1.0000x reference)
//
#include <hip/hip_runtime.h>

typedef unsigned short u16;
typedef unsigned int   u32;

// ---------- bf16 helpers ----------
__device__ __forceinline__ float bf2f(u16 h) { return __uint_as_float(((u32)h) << 16); }
__device__ __forceinline__ u16 f2bf(float f) {
    u32 u = __float_as_uint(f);
    u32 r = u + 0x7fffu + ((u >> 16) & 1u);   // RNE
    return (u16)(r >> 16);
}
__device__ __forceinline__ void unpack2(u32 v, float& a, float& b) {
    a = __uint_as_float(v << 16);
    b = __uint_as_float(v & 0xffff0000u);
}
__device__ __forceinline__ void load8(const u16* p, float* f) {   // bf16 x8
    uint4 u = *(const uint4*)p;
    unpack2(u.x, f[0], f[1]); unpack2(u.y, f[2], f[3]);
    unpack2(u.z, f[4], f[5]); unpack2(u.w, f[6], f[7]);
}

// Constants: B=4, T=16 (img=b*16+t), C=64, HW=64, PS=8, L=1024, D=4096
// INPUTS FLOAT32. OUTPUT FLOAT32 (proven by rounds 0-6 error fingerprints).
// Internal tokens/probs bf16.
// Token map: j = t*64+(h>>3)*8+(w>>3) ; dd = c*64+(h&7)*8+(w&7)

// ---------------------------------------------------------------------------
// K1: depthwise 3x3 q,k convs -> token layout bf16
// ---------------------------------------------------------------------------
__global__ __launch_bounds__(256) void dwconv_qk(
    const float* __restrict__ x, const float* __restrict__ qw, const float* __restrict__ qb,
    const float* __restrict__ kw, const float* __restrict__ kb,
    u16* __restrict__ qtok, u16* __restrict__ ktok)
{
    int idx = blockIdx.x * 256 + threadIdx.x;          // [img(6)][c(6)][h(6)][w(6)]
    int w = idx & 63, h = (idx >> 6) & 63, c = (idx >> 12) & 63, img = idx >> 18;
    float qa = qb[c], ka = kb[c];
    const float* xp = x + ((size_t)((img << 6) + c) << 12);
    #pragma unroll
    for (int ky = 0; ky < 3; ky++) {
        int yy = h + ky - 1;
        if (yy < 0 || yy > 63) continue;
        #pragma unroll
        for (int kx = 0; kx < 3; kx++) {
            int xx = w + kx - 1;
            if (xx < 0 || xx > 63) continue;
            float xv = xp[(yy << 6) + xx];
            qa += xv * qw[c * 9 + ky * 3 + kx];
            ka += xv * kw[c * 9 + ky * 3 + kx];
        }
    }
    int b = img >> 4, t = img & 15;
    int j  = (t << 6) + ((h >> 3) << 3) + (w >> 3);
    int dd = (c << 6) + ((h & 7) << 3) + (w & 7);
    size_t o = ((size_t)((b << 10) + j) << 12) + dd;
    qtok[o] = f2bf(qa);
    ktok[o] = f2bf(ka);
}

// ---------------------------------------------------------------------------
// K2/K6: full 3x3 conv (64->64), SAME. 512 thr: one img, 16x16 px tile,
// 8px x 4cout regs/thread, cin chunked 32, weights+tile in LDS.
// IS_C=false: x(f32) -> vtok(bf16 tokens). IS_C=true: axt(bf16 tokens) -> f32 out + x.
// ---------------------------------------------------------------------------
template<bool IS_C>
__global__ __launch_bounds__(512) void conv_spatial(
    const float* __restrict__ xin, const u16* __restrict__ axt,
    const float* __restrict__ wgt, const float* __restrict__ bias,
    const float* __restrict__ xres, u16* __restrict__ dst16, float* __restrict__ dst32)
{
    __shared__ u16 wl[288][64];      // [cl*9+tap][cout]
    __shared__ u16 xt[32][18][24];   // [cl][row][col]

    int tid  = threadIdx.x;
    int img  = blockIdx.x >> 4, tile = blockIdx.x & 15;
    int h0   = (tile >> 2) * 16, w0 = (tile & 3) * 16;
    int b    = img >> 4, t = img & 15;
    int pg   = tid >> 4, cg = tid & 15;
    int r    = pg >> 1, chh = pg & 1;

    float acc[8][4];
    #pragma unroll
    for (int i = 0; i < 8; i++)
        #pragma unroll
        for (int q = 0; q < 4; q++) acc[i][q] = 0.f;

    for (int c0 = 0; c0 < 64; c0 += 32) {
        __syncthreads();
        for (int e = tid; e < 18432; e += 512) {
            int o = e & 63, k = e >> 6;
            int cl = k / 9, tap = k - cl * 9;
            wl[k][o] = f2bf(wgt[(o * 64 + c0 + cl) * 9 + tap]);
        }
        for (int job = tid; job < 576; job += 512) {
            int cl = job / 18, rr = job - cl * 18;
            int h = h0 + rr - 1;
            int cch = c0 + cl;
            #pragma unroll
            for (int cc = 0; cc < 18; cc++) {
                int ww = w0 + cc - 1;
                u16 uv = 0;
                if (h >= 0 && h < 64 && ww >= 0 && ww < 64) {
                    if (!IS_C)
                        uv = f2bf(xin[((size_t)((img << 6) + cch) << 12) + (h << 6) + ww]);
                    else
                        uv = axt[((size_t)((b << 10) + (t << 6) + ((h >> 3) << 3) + (ww >> 3)) << 12)
                                 + (cch << 6) + ((h & 7) << 3) + (ww & 7)];
                }
                xt[cl][rr][cc] = uv;
            }
        }
        __syncthreads();

        for (int cl = 0; cl < 32; cl++) {
            #pragma unroll
            for (int dy = 0; dy < 3; dy++) {
                float xr[10];
                #pragma unroll
                for (int cc = 0; cc < 10; cc++) xr[cc] = bf2f(xt[cl][r + dy][chh * 8 + cc]);
                #pragma unroll
                for (int dx = 0; dx < 3; dx++) {
                    uint2 wv = *(const uint2*)&wl[cl * 9 + dy * 3 + dx][cg * 4];
                    float wq[4];
                    unpack2(wv.x, wq[0], wq[1]); unpack2(wv.y, wq[2], wq[3]);
                    #pragma unroll
                    for (int i = 0; i < 8; i++)
                        #pragma unroll
                        for (int q = 0; q < 4; q++)
                            acc[i][q] += xr[dx + i] * wq[q];
                }
            }
        }
    }

    int hh = h0 + r;
    if (!IS_C) {
        int gh = hh >> 3, gw = (w0 >> 3) + chh;
        int j  = (t << 6) + (gh << 3) + gw;
        int pr = hh & 7;
        #pragma unroll
        for (int q = 0; q < 4; q++) {
            int cout = cg * 4 + q;
            float bv = bias[cout];
            union { u16 h[8]; uint4 u; } pk;
            #pragma unroll
            for (int i = 0; i < 8; i++) pk.h[i] = f2bf(acc[i][q] + bv);
            *(uint4*)&dst16[((size_t)((b << 10) + j) << 12) + (cout << 6) + (pr << 3)] = pk.u;
        }
    } else {
        int wb = w0 + chh * 8;
        #pragma unroll
        for (int q = 0; q < 4; q++) {
            int cout = cg * 4 + q;
            float bv = bias[cout];
            size_t oidx = ((size_t)((img << 6) + cout) << 12) + (hh << 6) + wb;
            float4 xa = *(const float4*)&xres[oidx];
            float4 xb = *(const float4*)&xres[oidx + 4];
            float4 o0 = make_float4(acc[0][q] + bv + xa.x, acc[1][q] + bv + xa.y,
                                    acc[2][q] + bv + xa.z, acc[3][q] + bv + xa.w);
            float4 o1 = make_float4(acc[4][q] + bv + xb.x, acc[5][q] + bv + xb.y,
                                    acc[6][q] + bv + xb.z, acc[7][q] + bv + xb.w);
            *(float4*)&dst32[oidx]     = o0;
            *(float4*)&dst32[oidx + 4] = o1;
        }
    }
}

// ---------------------------------------------------------------------------
// K3: probs~ = exp(score/64) bf16 (max-free; |s/64| <= ~10, no overflow)
// 128x128 tile, 8x8/thread, Kc=32
// ---------------------------------------------------------------------------
__global__ __launch_bounds__(256) void scores_probs_kernel(
    const u16* __restrict__ q, const u16* __restrict__ k, u16* __restrict__ probs)
{
    __shared__ u16 qT[32][128];
    __shared__ u16 kT[32][128];
    int tid = threadIdx.x;
    int bi = blockIdx.x >> 6, tile = blockIdx.x & 63;
    int i0 = (tile >> 3) * 128, j0 = (tile & 7) * 128;
    int ti = tid >> 4, tj = tid & 15;

    float acc[8][8];
    #pragma unroll
    for (int a = 0; a < 8; a++)
        #pragma unroll
        for (int c = 0; c < 8; c++) acc[a][c] = 0.f;

    int rr = tid >> 1, cc0 = (tid & 1) * 16;
    const u16* qp = q + ((size_t)((bi << 10) + i0 + rr) << 12) + cc0;
    const u16* kp = k + ((size_t)((bi << 10) + j0 + rr) << 12) + cc0;

    for (int d0 = 0; d0 < 4096; d0 += 32) {
        uint4 a0 = *(const uint4*)(qp + d0);
        uint4 a1 = *(const uint4*)(qp + d0 + 8);
        uint4 b0 = *(const uint4*)(kp + d0);
        uint4 b1 = *(const uint4*)(kp + d0 + 8);
        union { uint4 u; u16 h[8]; } ua;
        ua.u = a0;
        #pragma unroll
        for (int m = 0; m < 8; m++) qT[cc0 + m][rr] = ua.h[m];
        ua.u = a1;
        #pragma unroll
        for (int m = 0; m < 8; m++) qT[cc0 + 8 + m][rr] = ua.h[m];
        ua.u = b0;
        #pragma unroll
        for (int m = 0; m < 8; m++) kT[cc0 + m][rr] = ua.h[m];
        ua.u = b1;
        #pragma unroll
        for (int m = 0; m < 8; m++) kT[cc0 + 8 + m][rr] = ua.h[m];
        __syncthreads();
        #pragma unroll 4
        for (int kk = 0; kk < 32; kk++) {
            float a8[8], b8[8];
            load8(&qT[kk][ti * 8], a8);
            load8(&kT[kk][tj * 8], b8);
            #pragma unroll
            for (int a = 0; a < 8; a++)
                #pragma unroll
                for (int c = 0; c < 8; c++) acc[a][c] += a8[a] * b8[c];
        }
        __syncthreads();
    }

    const float sc = 0.015625f;
    #pragma unroll
    for (int a = 0; a < 8; a++) {
        u16* dr = probs + ((size_t)((bi << 10) + i0 + ti * 8 + a) << 10) + j0 + tj * 8;
        union { u16 h[8]; uint4 u; } pk;
        #pragma unroll
        for (int c = 0; c < 8; c++) pk.h[c] = f2bf(__expf(acc[a][c] * sc));
        *(uint4*)dr = pk.u;
    }
}

// ---------------------------------------------------------------------------
// K4: invl[row] = 1 / sum_j probs~[row][j]
// ---------------------------------------------------------------------------
__global__ __launch_bounds__(256) void rowsum_inv_kernel(
    const u16* __restrict__ p, float* __restrict__ invl)
{
    int row = blockIdx.x, tid = threadIdx.x;
    uint2 v = ((const uint2*)(p + ((size_t)row << 10)))[tid];
    float a, b, c, d;
    unpack2(v.x, a, b); unpack2(v.y, c, d);
    float s = (a + b) + (c + d);
    #pragma unroll
    for (int off = 32; off; off >>= 1) s += __shfl_xor(s, off);
    __shared__ float rs[4];
    if ((tid & 63) == 0) rs[tid >> 6] = s;
    __syncthreads();
    if (tid == 0) invl[row] = 1.f / ((rs[0] + rs[1]) + (rs[2] + rs[3]));
}

// ---------------------------------------------------------------------------
// K5: ax = invl * (probs~ @ vtok). 128x128 tile, 8x8/thread, Kc=32
// ---------------------------------------------------------------------------
__global__ __launch_bounds__(256) void ax_kernel(
    const u16* __restrict__ p, const u16* __restrict__ v,
    const float* __restrict__ invl, u16* __restrict__ ax)
{
    __shared__ u16 aT[32][128];
    __shared__ u16 bt[32][128];
    int tid = threadIdx.x;
    int bi = blockIdx.x >> 8, rem = blockIdx.x & 255;
    int i0 = (rem >> 5) * 128, n0 = (rem & 31) * 128;
    int ti = tid >> 4, tj = tid & 15;

    float acc[8][8];
    #pragma unroll
    for (int a = 0; a < 8; a++)
        #pragma unroll
        for (int c = 0; c < 8; c++) acc[a][c] = 0.f;

    int rr = tid >> 1, cc0 = (tid & 1) * 16;
    int rr2 = tid >> 3, cc2 = (tid & 7) * 16;
    const u16* ap = p + ((size_t)((bi << 10) + i0 + rr) << 10) + cc0;

    for (int jj0 = 0; jj0 < 1024; jj0 += 32) {
        uint4 a0 = *(const uint4*)(ap + jj0);
        uint4 a1 = *(const uint4*)(ap + jj0 + 8);
        union { uint4 u; u16 h[8]; } ua;
        ua.u = a0;
        #pragma unroll
        for (int m = 0; m < 8; m++) aT[cc0 + m][rr] = ua.h[m];
        ua.u = a1;
        #pragma unroll
        for (int m = 0; m < 8; m++) aT[cc0 + 8 + m][rr] = ua.h[m];
        const u16* vp = v + ((size_t)((bi << 10) + jj0 + rr2) << 12) + n0 + cc2;
        *(uint4*)&bt[rr2][cc2]     = *(const uint4*)vp;
        *(uint4*)&bt[rr2][cc2 + 8] = *(const uint4*)(vp + 8);
        __syncthreads();
        #pragma unroll 4
        for (int kk = 0; kk < 32; kk++) {
            float a8[8], b8[8];
            load8(&aT[kk][ti * 8], a8);
            load8(&bt[kk][tj * 8], b8);
            #pragma unroll
            for (int a = 0; a < 8; a++)
                #pragma unroll
                for (int c = 0; c < 8; c++) acc[a][c] += a8[a] * b8[c];
        }
        __syncthreads();
    }

    #pragma unroll
    for (int a = 0; a < 8; a++) {
        float il = invl[(bi << 10) + i0 + ti * 8 + a];
        u16* dr = ax + ((size_t)((bi << 10) + i0 + ti * 8 + a) << 12) + n0 + tj * 8;
        union { u16 h[8]; uint4 u; } pk;
        #pragma unroll
        for (int c = 0; c < 8; c++) pk.h[c] = f2bf(acc[a][c] * il);
        *(uint4*)dr = pk.u;
    }
}

// ---------------------------------------------------------------------------
// Buffers: d_out is 64MB (f32 out). Its first 32MB doubles as u16 scratch.
//   qtok  : d_out[0,32MB) u16   -> vtok after scores -> overwritten by f32 out
//   ktok  : ws[ 0,32MB)         -> axtok after scores
//   probs : ws[32,40MB)
//   invl  : ws[40MB,+16KB)
// Order: dwconv -> scores -> rowsum -> conv_v -> ax -> conv_c(f32 out)
// ---------------------------------------------------------------------------
extern "C" void kernel_launch(void* const* d_in, const int* in_sizes, int n_in,
                              void* d_out, int out_size, void* d_ws, size_t ws_size,
                              hipStream_t stream)
{
    const float* x  = (const float*)d_in[0];
    const float* qw = (const float*)d_in[1];
    const float* qb = (const float*)d_in[2];
    const float* kw = (const float*)d_in[3];
    const float* kb = (const float*)d_in[4];
    const float* vw = (const float*)d_in[5];
    const float* vb = (const float*)d_in[6];
    const float* cw = (const float*)d_in[7];
    const float* cb = (const float*)d_in[8];
    float* out = (float*)d_out;

    char* ws = (char*)d_ws;
    u16*   qtok  = (u16*)d_out;                              // scratch in d_out
    u16*   ktok  = (u16*)(ws);
    u16*   probs = (u16*)(ws + (size_t)32 * 1024 * 1024);
    float* invl  = (float*)(ws + (size_t)40 * 1024 * 1024);
    u16*   vtok  = qtok;                                     // qtok dead after scores
    u16*   axtok = ktok;                                     // ktok dead after scores

    dwconv_qk<<<65536, 256, 0, stream>>>(x, qw, qb, kw, kb, qtok, ktok);
    scores_probs_kernel<<<256, 256, 0, stream>>>(qtok, ktok, probs);
    rowsum_inv_kernel<<<4096, 256, 0, stream>>>(probs, invl);
    conv_spatial<false><<<1024, 512, 0, stream>>>(x, nullptr, vw, vb, nullptr, vtok, nullptr);
    ax_kernel<<<1024, 256, 0, stream>>>(probs, vtok, invl, axtok);
    conv_spatial<true><<<1024, 512, 0, stream>>>(nullptr, axtok, cw, cb, x, nullptr, out);
}